// Round 2
// baseline (503.834 us; speedup 1.0000x reference)
//
#include <hip/hip_runtime.h>

#define H 51
#define TIN 512
#define TTOT 544      // TIN + future(32)
#define BTILE 4       // R16: 4 batch rows/block, 512 blocks -> 2 blocks/CU
#define AST 72        // ring row stride in shorts (144 B)
#define H2ST 5        // sH2f row stride in floats (5 coprime 32)
#define SOST 548      // sOut row stride in floats

typedef __attribute__((ext_vector_type(8))) short short8;
typedef __attribute__((ext_vector_type(4))) float float4v;

#define MFMA __builtin_amdgcn_mfma_f32_16x16x32_bf16

__device__ __forceinline__ float fast_rcp(float x) { return __builtin_amdgcn_rcpf(x); }
__device__ __forceinline__ float sigf(float x)  { return fast_rcp(1.0f + __expf(-x)); }
__device__ __forceinline__ float tanhf_(float x){ return 1.0f - 2.0f * fast_rcp(1.0f + __expf(2.0f * x)); }

__device__ __forceinline__ unsigned short bf16rnd(float x) {
    unsigned int u = __float_as_uint(x);
    return (unsigned short)((u + 0x7fffu + ((u >> 16) & 1u)) >> 16);
}
__device__ __forceinline__ void bf16split(float x, unsigned short& hi, float& lo) {
    unsigned int u  = __float_as_uint(x);
    unsigned int hr = (u + 0x7fffu + ((u >> 16) & 1u)) & 0xffff0000u;
    hi = (unsigned short)(hr >> 16);
    lo = x - __uint_as_float(hr);          // exact residual
}

// L1 k-space (A = sA1): 0..50 h1 | 51 x | 52..63 zero.
__device__ __forceinline__ float b1val(int k, int u, int g,
                                       const float* Whh1, const float* Wih1) {
    if (u >= H) return 0.0f;
    const int r = g * H + u;
    if (k < H)  return Whh1[r * H + k];
    if (k == H) return Wih1[r];
    return 0.0f;
}
// L2 k-space: 0..50 h1 (sA1) | 51..63 zero | 64..114 h2 (sA2 cols 0..50).
__device__ __forceinline__ float b2val(int k, int u, int g,
                                       const float* Wih2, const float* Whh2) {
    if (u >= H) return 0.0f;
    const int r = g * H + u;
    if (k < H) return Wih2[r * H + k];
    if (k >= 64 && k < 64 + H) return Whh2[r * H + (k - 64)];
    return 0.0f;
}

// R16 = R15 with occupancy doubled: BTILE 8->4, grid 256->512 -> 2 independent
// blocks per CU. The per-step barrier/dep-chain stall (~50% of 1875 cyc/step,
// unremovable within one block) is overlapped by the co-resident block.
//  - quad q owns ONE batch row (A-ring row 4q, MFMA reg 0). Per-block VALU
//    halves; total CU VALU unchanged; MFMA issue doubles (21% -> ~40%, room).
//  - waves_per_eu (2,2)->(4,4): the old cap would forbid co-residency.
//  - LDS ~34 KB/block (2x34 < 160), VGPR must stay <=128 for 4 waves/SIMD.
// Numerics per batch row identical -> absmax must stay 2.441e-4 exactly.
// Revert point if slower or absmax moves: R15 (425 us counter / 465 wall).
__global__ __launch_bounds__(512)
__attribute__((amdgpu_waves_per_eu(4, 4)))
void lstm_seq(
    const float* __restrict__ input,   // [2048][512]
    const float* __restrict__ W_ih1,   // [204]
    const float* __restrict__ W_hh1,   // [204][51]
    const float* __restrict__ b_ih1,   // [204]
    const float* __restrict__ b_hh1,   // [204]
    const float* __restrict__ W_ih2,   // [204][51]
    const float* __restrict__ W_hh2,   // [204][51]
    const float* __restrict__ b_ih2,   // [204]
    const float* __restrict__ b_hh2,   // [204]
    const float* __restrict__ W_lin,   // [51]
    const float* __restrict__ b_lin,   // [1]
    float* __restrict__ out)           // [2048][544]
{
    __shared__ __align__(16) unsigned short sA1h[2][16][AST];  // h1 ring + x col 51
    __shared__ __align__(16) unsigned short sA2h[2][16][AST];  // h2 ring
    __shared__ float sH2f[2][64][H2ST];                        // h2 f32 for head
    __shared__ __align__(8) float sXlo[2][BTILE];              // x bf16-residual
    __shared__ float sWlin[64];
    __shared__ __align__(16) float sIn[BTILE][TIN];            // staged input tile
    __shared__ __align__(16) float sOut[BTILE][SOST];          // buffered outputs

    const int tid  = threadIdx.x;
    const int lane = tid & 63;
    const int wv   = tid >> 6;             // 0..7
    const int Lw   = wv >> 2;              // 0: L1+head waves, 1: L2 waves
    const int ut   = wv & 3;
    const int quad = lane >> 4;
    const int kq   = quad * 8;
    const int nl   = lane & 15;
    const int u    = ut * 16 + nl;
    const int ur   = (u < H) ? u : (H - 1);
    const int b0   = blockIdx.x * BTILE;
    const float blin = b_lin[0];
    const int arow = quad * 4;             // A-ring row this quad writes; batch = quad
    const int kc   = lane & 31;            // head: k-phase
    const int bhead= 2 * ut + (lane >> 5); // head: candidate batch (valid if < BTILE)
    const bool headok = (bhead < BTILE);   // wave-half-uniform

    // ---- LDS init + input staging ----
    {
        unsigned short* p0 = &sA1h[0][0][0];
        unsigned short* p2 = &sA2h[0][0][0];
        for (int i = tid; i < 2 * 16 * AST; i += 512) { p0[i] = 0; p2[i] = 0; }
        float* pf = &sH2f[0][0][0];
        for (int i = tid; i < 2 * 64 * H2ST; i += 512) pf[i] = 0.0f;
        if (tid < 2 * BTILE) sXlo[tid >> 2][tid & 3] = 0.0f;
        if (tid < 64) sWlin[tid] = (tid < H) ? W_lin[tid] : 0.0f;
        // stage input tile: 4 rows x 512 f32, one float4 per thread, coalesced
        const int r = tid >> 7, l = tid & 127;
        const float* src = input + (size_t)(b0 + r) * TIN;
        *(float4v*)&sIn[r][l * 4] = *(const float4v*)&src[l * 4];
    }
    __syncthreads();
    if (tid < BTILE) {   // x(0) -> slot 0: bf16 hi in A col 51 (row 4*batch), residual
        unsigned short hh; float lo;
        bf16split(sIn[tid][0], hh, lo);
        sA1h[0][4 * tid][51] = hh;
        sXlo[0][tid] = lo;
    }
    __syncthreads();

    if (Lw == 0) {
        // ================= LAYER-1 + HEAD WAVES =================
        short8 B1h[4][2];
        float zb1[4], wxf[4];
        #pragma unroll
        for (int g = 0; g < 4; ++g) {
            #pragma unroll
            for (int kt = 0; kt < 2; ++kt)
                #pragma unroll
                for (int j = 0; j < 8; ++j)
                    B1h[g][kt][j] = (short)bf16rnd(b1val(kt * 32 + kq + j, u, g, W_hh1, W_ih1));
            const int r = g * H + ur;
            zb1[g] = b_ih1[r] + b_hh1[r];
            wxf[g] = W_ih1[r];             // f32 x-weight for residual fix
        }
        float c1 = 0.0f;

        auto l1work = [&](int rs, int ws) __attribute__((always_inline)) {
            short8 a0h = *(const short8*)&sA1h[rs][nl][kq];
            short8 a1h = *(const short8*)&sA1h[rs][nl][32 + kq];
            float xr = sXlo[rs][quad];     // residual for my row
            float4v C[4];
            #pragma unroll
            for (int g = 0; g < 4; ++g) {
                float4v c = {zb1[g], zb1[g], zb1[g], zb1[g]};
                c = MFMA(a0h, B1h[g][0], c, 0, 0, 0);
                c = MFMA(a1h, B1h[g][1], c, 0, 0, 0);
                C[g] = c;
            }
            float I = sigf  (C[0][0] + wxf[0] * xr);
            float F = sigf  (C[1][0] + wxf[1] * xr);
            float G = tanhf_(C[2][0] + wxf[2] * xr);
            float O = sigf  (C[3][0] + wxf[3] * xr);
            c1 = F * c1 + I * G;
            float h1v = O * tanhf_(c1);
            if (u < H) sA1h[ws][arow][u] = bf16rnd(h1v);
        };
        auto headw = [&](int slot, int outt) __attribute__((always_inline)) -> float {
            float val = 0.0f;
            if (headok) {
                float p = sWlin[kc]      * sH2f[slot][kc][bhead]
                        + sWlin[kc + 32] * sH2f[slot][kc + 32][bhead];
                p += __shfl_xor(p, 1);  p += __shfl_xor(p, 2);  p += __shfl_xor(p, 4);
                p += __shfl_xor(p, 8);  p += __shfl_xor(p, 16);
                val = p + blin;
                if (kc == 0) sOut[bhead][outt] = val;
            }
            return val;
        };
        auto teach = [&](int s, int rs, int ws) __attribute__((always_inline)) {
            float xpre = 0.0f;
            const bool doX = (wv == 1) && (lane < BTILE) && (s + 1 < TIN);
            if (doX) xpre = sIn[lane][s + 1];
            if (s >= 2) headw(ws, s - 2);      // sH2f[ws] written last step
            l1work(rs, ws);
            if (doX) {
                unsigned short hh; float lo; bf16split(xpre, hh, lo);
                sA1h[ws][4 * lane][51] = hh;
                sXlo[ws][lane] = lo;
            }
            __syncthreads();
        };

        // ---- pipelined teacher-forced phase (static rs/ws) ----
        for (int s = 0; s < TIN; ++s) {
            if ((s & 1) == 0) teach(s, 0, 1);
            else              teach(s, 1, 0);
        }
        // ---- serial autoregressive tail ----
        for (int s = TIN; s <= TTOT; ++s) {
            const int rs = s & 1, ws = rs ^ 1;
            __syncthreads();               // B1: L2 finished h2(s-1) -> sH2f[rs]
            {
                float val = headw(rs, s - 1);
                if (headok && kc == 0) {   // feedback x(s) = out(s-1)
                    unsigned short hh; float lo; bf16split(val, hh, lo);
                    sA1h[rs][4 * bhead][51] = hh;
                    sXlo[rs][bhead] = lo;
                }
                if (s == TIN) headw(ws, s - 2);   // gap: out(TIN-2)
            }
            __syncthreads();               // B2: x(s) visible
            if (s < TTOT) l1work(rs, ws);
            __syncthreads();               // B3: h1(s) visible
        }
    } else {
        // ================= LAYER-2 WAVES =================
        short8 B2h[4][4];
        float zb2[4];
        #pragma unroll
        for (int g = 0; g < 4; ++g) {
            #pragma unroll
            for (int kt = 0; kt < 4; ++kt)
                #pragma unroll
                for (int j = 0; j < 8; ++j)
                    B2h[g][kt][j] = (short)bf16rnd(b2val(kt * 32 + kq + j, u, g, W_ih2, W_hh2));
            const int r = g * H + ur;
            zb2[g] = b_ih2[r] + b_hh2[r];
        }
        float c2 = 0.0f;

        auto l2work = [&](int rs, int ws) __attribute__((always_inline)) {
            short8 f0h = *(const short8*)&sA1h[rs][nl][kq];
            short8 f1h = *(const short8*)&sA1h[rs][nl][32 + kq];
            short8 f2h = *(const short8*)&sA2h[rs][nl][kq];
            short8 f3h = *(const short8*)&sA2h[rs][nl][32 + kq];
            float4v C[4];
            #pragma unroll
            for (int g = 0; g < 4; ++g) {
                float4v c = {zb2[g], zb2[g], zb2[g], zb2[g]};
                c = MFMA(f0h, B2h[g][0], c, 0, 0, 0);
                c = MFMA(f1h, B2h[g][1], c, 0, 0, 0);
                c = MFMA(f2h, B2h[g][2], c, 0, 0, 0);
                c = MFMA(f3h, B2h[g][3], c, 0, 0, 0);
                C[g] = c;
            }
            float I = sigf  (C[0][0]);
            float F = sigf  (C[1][0]);
            float G = tanhf_(C[2][0]);
            float O = sigf  (C[3][0]);
            c2 = F * c2 + I * G;
            float h2v = O * tanhf_(c2);
            if (u < H) {
                sA2h[ws][arow][u] = bf16rnd(h2v);
                sH2f[rs][u][quad] = h2v;
            }
        };

        // ---- pipelined teacher-forced phase ----
        for (int s = 0; s < TIN; ++s) {
            if ((s & 1) == 0) { if (s) l2work(0, 1); }
            else              l2work(1, 0);
            __syncthreads();
        }
        // ---- serial tail ----
        for (int s = TIN; s <= TTOT; ++s) {
            const int rs = s & 1, ws = rs ^ 1;
            l2work(rs, ws);
            __syncthreads();               // B1
            __syncthreads();               // B2
            __syncthreads();               // B3
        }
    }

    // ---- write buffered outputs back: 4 rows x 544 f32, float4 coalesced ----
    __syncthreads();
    for (int i = tid; i < BTILE * (TTOT / 4); i += 512) {
        const int r = i / (TTOT / 4);
        const int c = i - r * (TTOT / 4);
        *(float4v*)&out[(size_t)(b0 + r) * TTOT + c * 4] =
            *(const float4v*)&sOut[r][c * 4];
    }
}

extern "C" void kernel_launch(void* const* d_in, const int* in_sizes, int n_in,
                              void* d_out, int out_size, void* d_ws, size_t ws_size,
                              hipStream_t stream) {
    const float* input = (const float*)d_in[0];
    const float* W_ih1 = (const float*)d_in[1];
    const float* W_hh1 = (const float*)d_in[2];
    const float* b_ih1 = (const float*)d_in[3];
    const float* b_hh1 = (const float*)d_in[4];
    const float* W_ih2 = (const float*)d_in[5];
    const float* W_hh2 = (const float*)d_in[6];
    const float* b_ih2 = (const float*)d_in[7];
    const float* b_hh2 = (const float*)d_in[8];
    const float* W_lin = (const float*)d_in[9];
    const float* b_lin = (const float*)d_in[10];
    // d_in[11] = future (=32), compiled in.
    float* out = (float*)d_out;

    lstm_seq<<<dim3(512), dim3(512), 0, stream>>>(input, W_ih1, W_hh1, b_ih1, b_hh1,
                                                  W_ih2, W_hh2, b_ih2, b_hh2,
                                                  W_lin, b_lin, out);
}

// Round 3
// 391.287 us; speedup vs baseline: 1.2876x; 1.2876x over previous
//
#include <hip/hip_runtime.h>

#define H 51
#define TIN 512
#define TTOT 544      // TIN + future(32)
#define BTILE 8
#define AST 72        // ring row stride in shorts (144 B)
#define H2ST 13       // sH2f row stride in floats (13 coprime 32)
#define SOST 548      // sOut row stride in floats
#define NTHR 768      // 12 waves: 4 L1 + 4 L2 + 4 aux

typedef __attribute__((ext_vector_type(8))) short short8;
typedef __attribute__((ext_vector_type(4))) float float4v;

#define MFMA __builtin_amdgcn_mfma_f32_16x16x32_bf16

__device__ __forceinline__ float fast_rcp(float x) { return __builtin_amdgcn_rcpf(x); }
__device__ __forceinline__ float sigf(float x)  { return fast_rcp(1.0f + __expf(-x)); }
__device__ __forceinline__ float tanhf_(float x){ return 1.0f - 2.0f * fast_rcp(1.0f + __expf(2.0f * x)); }

__device__ __forceinline__ unsigned short bf16rnd(float x) {
    unsigned int u = __float_as_uint(x);
    return (unsigned short)((u + 0x7fffu + ((u >> 16) & 1u)) >> 16);
}
// RNE pack of two f32 -> two bf16 in one instruction (same rounding as bf16rnd)
__device__ __forceinline__ unsigned int bf16pk(float a, float b) {
    unsigned int r;
    asm("v_cvt_pk_bf16_f32 %0, %1, %2" : "=v"(r) : "v"(a), "v"(b));
    return r;
}
__device__ __forceinline__ void bf16split(float x, unsigned short& hi, float& lo) {
    unsigned int u  = __float_as_uint(x);
    unsigned int hr = (u + 0x7fffu + ((u >> 16) & 1u)) & 0xffff0000u;
    hi = (unsigned short)(hr >> 16);
    lo = x - __uint_as_float(hr);          // exact residual
}

// L1 k-space (A = sA1): 0..50 h1 | 51 x | 52..63 zero.
__device__ __forceinline__ float b1val(int k, int u, int g,
                                       const float* Whh1, const float* Wih1) {
    if (u >= H) return 0.0f;
    const int r = g * H + u;
    if (k < H)  return Whh1[r * H + k];
    if (k == H) return Wih1[r];
    return 0.0f;
}
// L2 k-space: 0..50 h1 (sA1) | 51..63 zero | 64..114 h2 (sA2 cols 0..50).
__device__ __forceinline__ float b2val(int k, int u, int g,
                                       const float* Wih2, const float* Whh2) {
    if (u >= H) return 0.0f;
    const int r = g * H + u;
    if (k < H) return Wih2[r * H + k];
    if (k >= 64 && k < 64 + H) return Whh2[r * H + (k - 64)];
    return 0.0f;
}

// R17 = R15 structure (BTILE 8, grid 256 — R16's batch-split co-residency paid
// a 2x M-waste tax, -14%) + two stall-attacks that add NO MFMA work:
//  (1) 4 aux waves (12 waves total, 3/SIMD): head shuffle-reduce + x staging +
//      tail feedback move off the L1 waves. L1 critical wave sheds ~25 inst;
//      the 3rd wave per SIMD fills post-barrier stall holes.
//  (2) v_cvt_pk_bf16_f32 packs the h-pair rounding: ~8 VALU -> 3 in l1work and
//      l2work. RNE == RNE -> bit-identical, absmax must stay 2.441e-4.
// Revert point if slower: R15 (425 us counter).
__global__ __launch_bounds__(NTHR)
__attribute__((amdgpu_waves_per_eu(3, 3)))
void lstm_seq(
    const float* __restrict__ input,   // [2048][512]
    const float* __restrict__ W_ih1,   // [204]
    const float* __restrict__ W_hh1,   // [204][51]
    const float* __restrict__ b_ih1,   // [204]
    const float* __restrict__ b_hh1,   // [204]
    const float* __restrict__ W_ih2,   // [204][51]
    const float* __restrict__ W_hh2,   // [204][51]
    const float* __restrict__ b_ih2,   // [204]
    const float* __restrict__ b_hh2,   // [204]
    const float* __restrict__ W_lin,   // [51]
    const float* __restrict__ b_lin,   // [1]
    float* __restrict__ out)           // [2048][544]
{
    __shared__ __align__(16) unsigned short sA1h[2][16][AST];  // h1 ring + x col 51
    __shared__ __align__(16) unsigned short sA2h[2][16][AST];  // h2 ring
    __shared__ float sH2f[2][64][H2ST];                        // h2 f32 for head
    __shared__ __align__(8) float sXlo[2][8];                  // x bf16-residual
    __shared__ float sWlin[64];
    __shared__ __align__(16) float sIn[BTILE][TIN];            // staged input tile
    __shared__ __align__(16) float sOut[BTILE][SOST];          // buffered outputs

    const int tid  = threadIdx.x;
    const int lane = tid & 63;
    const int wv   = tid >> 6;             // 0..11
    const int ut   = wv & 3;
    const int quad = lane >> 4;
    const int kq   = quad * 8;
    const int nl   = lane & 15;
    const int u    = ut * 16 + nl;
    const int ur   = (u < H) ? u : (H - 1);
    const int b0   = blockIdx.x * BTILE;
    const float blin = b_lin[0];
    const int rowA = (quad & 1) * 4 + (quad >> 1) * 2;   // this quad's 2 batch-rows
    const int arow = quad * 4;             // A-ring row this quad WRITES (relocated)
    const int kc   = lane & 31;            // head: k-phase
    const int bhead= 2 * ut + (lane >> 5); // head: this lane's batch

    // ---- LDS init + input staging ----
    {
        unsigned short* p0 = &sA1h[0][0][0];
        unsigned short* p2 = &sA2h[0][0][0];
        for (int i = tid; i < 2 * 16 * AST; i += NTHR) { p0[i] = 0; p2[i] = 0; }
        float* pf = &sH2f[0][0][0];
        for (int i = tid; i < 2 * 64 * H2ST; i += NTHR) pf[i] = 0.0f;
        if (tid < 16) sXlo[tid >> 3][tid & 7] = 0.0f;
        if (tid < 64) sWlin[tid] = (tid < H) ? W_lin[tid] : 0.0f;
        // stage input tile: 8 rows x 512 f32 = 1024 float4, coalesced
        for (int i = tid; i < BTILE * (TIN / 4); i += NTHR) {
            const int r = i >> 7, c = i & 127;
            *(float4v*)&sIn[r][c * 4] =
                *(const float4v*)&input[(size_t)(b0 + r) * TIN + c * 4];
        }
    }
    __syncthreads();
    if (tid < 8) {   // x(0) -> slot 0: bf16 hi in A col 51 (relocated row), residual
        unsigned short hh; float lo;
        bf16split(sIn[tid][0], hh, lo);
        sA1h[0][(tid & 2) ? tid + 6 : tid][51] = hh;
        sXlo[0][tid] = lo;
    }
    __syncthreads();

    if (wv < 4) {
        // ================= LAYER-1 WAVES =================
        short8 B1h[4][2];
        float zb1[4], wxf[4];
        #pragma unroll
        for (int g = 0; g < 4; ++g) {
            #pragma unroll
            for (int kt = 0; kt < 2; ++kt)
                #pragma unroll
                for (int j = 0; j < 8; ++j)
                    B1h[g][kt][j] = (short)bf16rnd(b1val(kt * 32 + kq + j, u, g, W_hh1, W_ih1));
            const int r = g * H + ur;
            zb1[g] = b_ih1[r] + b_hh1[r];
            wxf[g] = W_ih1[r];             // f32 x-weight for residual fix
        }
        float c1[2] = {0, 0};

        auto l1work = [&](int rs, int ws) __attribute__((always_inline)) {
            short8 a0h = *(const short8*)&sA1h[rs][nl][kq];
            short8 a1h = *(const short8*)&sA1h[rs][nl][32 + kq];
            float2 xl = *(const float2*)&sXlo[rs][rowA];   // residuals for my 2 rows
            float4v C[4];
            #pragma unroll
            for (int g = 0; g < 4; ++g) {
                float4v c = {zb1[g], zb1[g], zb1[g], zb1[g]};
                c = MFMA(a0h, B1h[g][0], c, 0, 0, 0);
                c = MFMA(a1h, B1h[g][1], c, 0, 0, 0);
                C[g] = c;
            }
            float h1v[2];
            #pragma unroll
            for (int j = 0; j < 2; ++j) {
                const float xr = j ? xl.y : xl.x;
                float I = sigf  (C[0][j] + wxf[0] * xr);
                float F = sigf  (C[1][j] + wxf[1] * xr);
                float G = tanhf_(C[2][j] + wxf[2] * xr);
                float O = sigf  (C[3][j] + wxf[3] * xr);
                c1[j] = F * c1[j] + I * G;
                h1v[j] = O * tanhf_(c1[j]);
            }
            if (u < H) {
                const unsigned int pk = bf16pk(h1v[0], h1v[1]);
                sA1h[ws][arow][u]     = (unsigned short)pk;
                sA1h[ws][arow + 1][u] = (unsigned short)(pk >> 16);
            }
        };

        // ---- pipelined teacher-forced phase (static rs/ws) ----
        for (int s = 0; s < TIN; ++s) {
            if ((s & 1) == 0) l1work(0, 1);
            else              l1work(1, 0);
            __syncthreads();
        }
        // ---- serial autoregressive tail ----
        for (int s = TIN; s <= TTOT; ++s) {
            const int rs = s & 1, ws = rs ^ 1;
            __syncthreads();               // B1: L2 finished h2(s-1) -> sH2f[rs]
            __syncthreads();               // B2: aux wrote x(s)
            if (s < TTOT) l1work(rs, ws);
            __syncthreads();               // B3: h1(s) visible
        }
    } else if (wv < 8) {
        // ================= LAYER-2 WAVES =================
        short8 B2h[4][4];
        float zb2[4];
        #pragma unroll
        for (int g = 0; g < 4; ++g) {
            #pragma unroll
            for (int kt = 0; kt < 4; ++kt)
                #pragma unroll
                for (int j = 0; j < 8; ++j)
                    B2h[g][kt][j] = (short)bf16rnd(b2val(kt * 32 + kq + j, u, g, W_ih2, W_hh2));
            const int r = g * H + ur;
            zb2[g] = b_ih2[r] + b_hh2[r];
        }
        float c2[2] = {0, 0};

        auto l2work = [&](int rs, int ws) __attribute__((always_inline)) {
            short8 f0h = *(const short8*)&sA1h[rs][nl][kq];
            short8 f1h = *(const short8*)&sA1h[rs][nl][32 + kq];
            short8 f2h = *(const short8*)&sA2h[rs][nl][kq];
            short8 f3h = *(const short8*)&sA2h[rs][nl][32 + kq];
            float4v C[4];
            #pragma unroll
            for (int g = 0; g < 4; ++g) {
                float4v c = {zb2[g], zb2[g], zb2[g], zb2[g]};
                c = MFMA(f0h, B2h[g][0], c, 0, 0, 0);
                c = MFMA(f1h, B2h[g][1], c, 0, 0, 0);
                c = MFMA(f2h, B2h[g][2], c, 0, 0, 0);
                c = MFMA(f3h, B2h[g][3], c, 0, 0, 0);
                C[g] = c;
            }
            float h2v[2];
            #pragma unroll
            for (int j = 0; j < 2; ++j) {
                float I = sigf  (C[0][j]);
                float F = sigf  (C[1][j]);
                float G = tanhf_(C[2][j]);
                float O = sigf  (C[3][j]);
                c2[j] = F * c2[j] + I * G;
                h2v[j] = O * tanhf_(c2[j]);
            }
            if (u < H) {
                const unsigned int pk = bf16pk(h2v[0], h2v[1]);
                sA2h[ws][arow][u]     = (unsigned short)pk;
                sA2h[ws][arow + 1][u] = (unsigned short)(pk >> 16);
                sH2f[rs][u][rowA]     = h2v[0];
                sH2f[rs][u][rowA + 1] = h2v[1];
            }
        };

        // ---- pipelined teacher-forced phase ----
        for (int s = 0; s < TIN; ++s) {
            if ((s & 1) == 0) { if (s) l2work(0, 1); }
            else              l2work(1, 0);
            __syncthreads();
        }
        // ---- serial tail ----
        for (int s = TIN; s <= TTOT; ++s) {
            const int rs = s & 1, ws = rs ^ 1;
            l2work(rs, ws);
            __syncthreads();               // B1
            __syncthreads();               // B2
            __syncthreads();               // B3
        }
    } else {
        // ================= AUX WAVES: head + x staging + feedback =================
        auto headw = [&](int slot, int outt) __attribute__((always_inline)) -> float {
            float p = sWlin[kc]      * sH2f[slot][kc][bhead]
                    + sWlin[kc + 32] * sH2f[slot][kc + 32][bhead];
            p += __shfl_xor(p, 1);  p += __shfl_xor(p, 2);  p += __shfl_xor(p, 4);
            p += __shfl_xor(p, 8);  p += __shfl_xor(p, 16);
            float val = p + blin;
            if (kc == 0) sOut[bhead][outt] = val;
            return val;
        };

        // ---- teacher phase: head(s-2) + stage x(s+1) ----
        for (int s = 0; s < TIN; ++s) {
            const int ws = (s & 1) ? 0 : 1;
            if (s >= 2) headw(ws, s - 2);      // sH2f[ws] written last interval
            if ((wv == 8) && (lane < 8) && (s + 1 < TIN)) {
                unsigned short hh; float lo; bf16split(sIn[lane][s + 1], hh, lo);
                sA1h[ws][(lane & 2) ? lane + 6 : lane][51] = hh;
                sXlo[ws][lane] = lo;
            }
            __syncthreads();
        }
        // ---- serial tail: head(s-1) + feedback x(s) ----
        for (int s = TIN; s <= TTOT; ++s) {
            const int rs = s & 1, ws = rs ^ 1;
            __syncthreads();               // B1: h2(s-1) -> sH2f[rs] visible
            {
                float val = headw(rs, s - 1);
                if (kc == 0 && s < TTOT) { // feedback x(s) = out(s-1)
                    unsigned short hh; float lo; bf16split(val, hh, lo);
                    sA1h[rs][(bhead & 2) ? bhead + 6 : bhead][51] = hh;
                    sXlo[rs][bhead] = lo;
                }
                if (s == TIN) headw(ws, s - 2);   // gap: out(TIN-2)
            }
            __syncthreads();               // B2: x(s) visible
            __syncthreads();               // B3
        }
    }

    // ---- write buffered outputs back: 8 rows x 544 f32, float4 coalesced ----
    __syncthreads();
    for (int i = tid; i < BTILE * (TTOT / 4); i += NTHR) {
        const int r = i / (TTOT / 4);
        const int c = i - r * (TTOT / 4);
        *(float4v*)&out[(size_t)(b0 + r) * TTOT + c * 4] =
            *(const float4v*)&sOut[r][c * 4];
    }
}

extern "C" void kernel_launch(void* const* d_in, const int* in_sizes, int n_in,
                              void* d_out, int out_size, void* d_ws, size_t ws_size,
                              hipStream_t stream) {
    const float* input = (const float*)d_in[0];
    const float* W_ih1 = (const float*)d_in[1];
    const float* W_hh1 = (const float*)d_in[2];
    const float* b_ih1 = (const float*)d_in[3];
    const float* b_hh1 = (const float*)d_in[4];
    const float* W_ih2 = (const float*)d_in[5];
    const float* W_hh2 = (const float*)d_in[6];
    const float* b_ih2 = (const float*)d_in[7];
    const float* b_hh2 = (const float*)d_in[8];
    const float* W_lin = (const float*)d_in[9];
    const float* b_lin = (const float*)d_in[10];
    // d_in[11] = future (=32), compiled in.
    float* out = (float*)d_out;

    lstm_seq<<<dim3(256), dim3(NTHR), 0, stream>>>(input, W_ih1, W_hh1, b_ih1, b_hh1,
                                                   W_ih2, W_hh2, b_ih2, b_hh2,
                                                   W_lin, b_lin, out);
}

// Round 7
// 390.320 us; speedup vs baseline: 1.2908x; 1.0025x over previous
//
#include <hip/hip_runtime.h>

#define H 51
#define TIN 512
#define TTOT 544      // TIN + future(32)
#define BTILE 8
#define AST 88        // ring row stride in shorts (176 B = 44 dw, 16B-aligned):
                      // ds_read_b128 bank-start 12*nl mod 32 -> 2-way (free, m136).
                      // was 72 (8-way), R18-R20 used 80 (4-way).
#define H2ST 13       // sH2f row stride in floats (13 coprime 32)
#define SOST 548      // sOut row stride in floats
#define NTHR 768      // 12 waves: 4 L1 + 4 L2 + 4 aux

typedef __attribute__((ext_vector_type(8))) short short8;
typedef __attribute__((ext_vector_type(4))) float float4v;

#define MFMA __builtin_amdgcn_mfma_f32_16x16x32_bf16

__device__ __forceinline__ float fast_rcp(float x) { return __builtin_amdgcn_rcpf(x); }
__device__ __forceinline__ float sigf(float x)  { return fast_rcp(1.0f + __expf(-x)); }
__device__ __forceinline__ float tanhf_(float x){ return 1.0f - 2.0f * fast_rcp(1.0f + __expf(2.0f * x)); }

__device__ __forceinline__ unsigned short bf16rnd(float x) {
    unsigned int u = __float_as_uint(x);
    return (unsigned short)((u + 0x7fffu + ((u >> 16) & 1u)) >> 16);
}
// RNE pack of two f32 -> two bf16 in one instruction (same rounding as bf16rnd)
__device__ __forceinline__ unsigned int bf16pk(float a, float b) {
    unsigned int r;
    asm("v_cvt_pk_bf16_f32 %0, %1, %2" : "=v"(r) : "v"(a), "v"(b));
    return r;
}
__device__ __forceinline__ void bf16split(float x, unsigned short& hi, float& lo) {
    unsigned int u  = __float_as_uint(x);
    unsigned int hr = (u + 0x7fffu + ((u >> 16) & 1u)) & 0xffff0000u;
    hi = (unsigned short)(hr >> 16);
    lo = x - __uint_as_float(hr);          // exact residual
}

// L1 k-space (A = sA1): 0..50 h1 | 51 x | 52..63 zero.
__device__ __forceinline__ float b1val(int k, int u, int g,
                                       const float* Whh1, const float* Wih1) {
    if (u >= H) return 0.0f;
    const int r = g * H + u;
    if (k < H)  return Whh1[r * H + k];
    if (k == H) return Wih1[r];
    return 0.0f;
}
// L2 k-space: 0..50 h1 (sA1) | 51..63 zero | 64..114 h2 (sA2 cols 0..50).
__device__ __forceinline__ float b2val(int k, int u, int g,
                                       const float* Wih2, const float* Whh2) {
    if (u >= H) return 0.0f;
    const int r = g * H + u;
    if (k < H) return Wih2[r * H + k];
    if (k >= 64 && k < 64 + H) return Whh2[r * H + (k - 64)];
    return 0.0f;
}

// R21 = R17 numerics VERBATIM (the passing 350 us kernel) + AST 72->88 only.
// LESSON (R18-R20, 3 failed rounds): the recurrence numerics must be
// BIT-IDENTICAL to the canonical formulation, not merely accurate -- the
// 32-step autoregressive tail (out feeds back as x) amplifies any f32-ulp
// perturbation by the per-step Jacobian (>1.5) to O(0.1) at the output.
// 13 rounds of absmax pinned at exactly 2.441e-4 = evidence every passing
// kernel was bit-exact. NUMERICS ARE FROZEN: sigf/tanhf_ (__expf+fast_rcp),
// separate c-update, bf16pk h-store. Optimize structure/memory only.
// AST=88: ds_read_b128 ring reads go 8-way -> 2-way bank conflict (free).
// Revert if absmax != 2.441e-4 or slower: R17 (350 us counter).
__global__ __launch_bounds__(NTHR)
__attribute__((amdgpu_waves_per_eu(3, 3)))
void lstm_seq(
    const float* __restrict__ input,   // [2048][512]
    const float* __restrict__ W_ih1,   // [204]
    const float* __restrict__ W_hh1,   // [204][51]
    const float* __restrict__ b_ih1,   // [204]
    const float* __restrict__ b_hh1,   // [204]
    const float* __restrict__ W_ih2,   // [204][51]
    const float* __restrict__ W_hh2,   // [204][51]
    const float* __restrict__ b_ih2,   // [204]
    const float* __restrict__ b_hh2,   // [204]
    const float* __restrict__ W_lin,   // [51]
    const float* __restrict__ b_lin,   // [1]
    float* __restrict__ out)           // [2048][544]
{
    __shared__ __align__(16) unsigned short sA1h[2][16][AST];  // h1 ring + x col 51
    __shared__ __align__(16) unsigned short sA2h[2][16][AST];  // h2 ring
    __shared__ float sH2f[2][64][H2ST];                        // h2 f32 for head
    __shared__ __align__(8) float sXlo[2][8];                  // x bf16-residual
    __shared__ float sWlin[64];
    __shared__ __align__(16) float sIn[BTILE][TIN];            // staged input tile
    __shared__ __align__(16) float sOut[BTILE][SOST];          // buffered outputs

    const int tid  = threadIdx.x;
    const int lane = tid & 63;
    const int wv   = tid >> 6;             // 0..11
    const int ut   = wv & 3;
    const int quad = lane >> 4;
    const int kq   = quad * 8;
    const int nl   = lane & 15;
    const int u    = ut * 16 + nl;
    const int ur   = (u < H) ? u : (H - 1);
    const int b0   = blockIdx.x * BTILE;
    const float blin = b_lin[0];
    const int rowA = (quad & 1) * 4 + (quad >> 1) * 2;   // this quad's 2 batch-rows
    const int arow = quad * 4;             // A-ring row this quad WRITES (relocated)
    const int kc   = lane & 31;            // head: k-phase
    const int bhead= 2 * ut + (lane >> 5); // head: this lane's batch

    // ---- LDS init + input staging ----
    {
        unsigned short* p0 = &sA1h[0][0][0];
        unsigned short* p2 = &sA2h[0][0][0];
        for (int i = tid; i < 2 * 16 * AST; i += NTHR) { p0[i] = 0; p2[i] = 0; }
        float* pf = &sH2f[0][0][0];
        for (int i = tid; i < 2 * 64 * H2ST; i += NTHR) pf[i] = 0.0f;
        if (tid < 16) sXlo[tid >> 3][tid & 7] = 0.0f;
        if (tid < 64) sWlin[tid] = (tid < H) ? W_lin[tid] : 0.0f;
        // stage input tile: 8 rows x 512 f32 = 1024 float4, coalesced
        for (int i = tid; i < BTILE * (TIN / 4); i += NTHR) {
            const int r = i >> 7, c = i & 127;
            *(float4v*)&sIn[r][c * 4] =
                *(const float4v*)&input[(size_t)(b0 + r) * TIN + c * 4];
        }
    }
    __syncthreads();
    if (tid < 8) {   // x(0) -> slot 0: bf16 hi in A col 51 (relocated row), residual
        unsigned short hh; float lo;
        bf16split(sIn[tid][0], hh, lo);
        sA1h[0][(tid & 2) ? tid + 6 : tid][51] = hh;
        sXlo[0][tid] = lo;
    }
    __syncthreads();

    if (wv < 4) {
        // ================= LAYER-1 WAVES =================
        short8 B1h[4][2];
        float zb1[4], wxf[4];
        #pragma unroll
        for (int g = 0; g < 4; ++g) {
            #pragma unroll
            for (int kt = 0; kt < 2; ++kt)
                #pragma unroll
                for (int j = 0; j < 8; ++j)
                    B1h[g][kt][j] = (short)bf16rnd(b1val(kt * 32 + kq + j, u, g, W_hh1, W_ih1));
            const int r = g * H + ur;
            zb1[g] = b_ih1[r] + b_hh1[r];
            wxf[g] = W_ih1[r];             // f32 x-weight for residual fix
        }
        float c1[2] = {0, 0};

        auto l1work = [&](int rs, int ws) __attribute__((always_inline)) {
            short8 a0h = *(const short8*)&sA1h[rs][nl][kq];
            short8 a1h = *(const short8*)&sA1h[rs][nl][32 + kq];
            float2 xl = *(const float2*)&sXlo[rs][rowA];   // residuals for my 2 rows
            float4v C[4];
            #pragma unroll
            for (int g = 0; g < 4; ++g) {
                float4v c = {zb1[g], zb1[g], zb1[g], zb1[g]};
                c = MFMA(a0h, B1h[g][0], c, 0, 0, 0);
                c = MFMA(a1h, B1h[g][1], c, 0, 0, 0);
                C[g] = c;
            }
            float h1v[2];
            #pragma unroll
            for (int j = 0; j < 2; ++j) {
                const float xr = j ? xl.y : xl.x;
                float I = sigf  (C[0][j] + wxf[0] * xr);
                float F = sigf  (C[1][j] + wxf[1] * xr);
                float G = tanhf_(C[2][j] + wxf[2] * xr);
                float O = sigf  (C[3][j] + wxf[3] * xr);
                c1[j] = F * c1[j] + I * G;
                h1v[j] = O * tanhf_(c1[j]);
            }
            if (u < H) {
                const unsigned int pk = bf16pk(h1v[0], h1v[1]);
                sA1h[ws][arow][u]     = (unsigned short)pk;
                sA1h[ws][arow + 1][u] = (unsigned short)(pk >> 16);
            }
        };

        // ---- pipelined teacher-forced phase (static rs/ws) ----
        for (int s = 0; s < TIN; ++s) {
            if ((s & 1) == 0) l1work(0, 1);
            else              l1work(1, 0);
            __syncthreads();
        }
        // ---- serial autoregressive tail ----
        for (int s = TIN; s <= TTOT; ++s) {
            const int rs = s & 1, ws = rs ^ 1;
            __syncthreads();               // B1: L2 finished h2(s-1) -> sH2f[rs]
            __syncthreads();               // B2: aux wrote x(s)
            if (s < TTOT) l1work(rs, ws);
            __syncthreads();               // B3: h1(s) visible
        }
    } else if (wv < 8) {
        // ================= LAYER-2 WAVES =================
        short8 B2h[4][4];
        float zb2[4];
        #pragma unroll
        for (int g = 0; g < 4; ++g) {
            #pragma unroll
            for (int kt = 0; kt < 4; ++kt)
                #pragma unroll
                for (int j = 0; j < 8; ++j)
                    B2h[g][kt][j] = (short)bf16rnd(b2val(kt * 32 + kq + j, u, g, W_ih2, W_hh2));
            const int r = g * H + ur;
            zb2[g] = b_ih2[r] + b_hh2[r];
        }
        float c2[2] = {0, 0};

        auto l2work = [&](int rs, int ws) __attribute__((always_inline)) {
            short8 f0h = *(const short8*)&sA1h[rs][nl][kq];
            short8 f1h = *(const short8*)&sA1h[rs][nl][32 + kq];
            short8 f2h = *(const short8*)&sA2h[rs][nl][kq];
            short8 f3h = *(const short8*)&sA2h[rs][nl][32 + kq];
            float4v C[4];
            #pragma unroll
            for (int g = 0; g < 4; ++g) {
                float4v c = {zb2[g], zb2[g], zb2[g], zb2[g]};
                c = MFMA(f0h, B2h[g][0], c, 0, 0, 0);
                c = MFMA(f1h, B2h[g][1], c, 0, 0, 0);
                c = MFMA(f2h, B2h[g][2], c, 0, 0, 0);
                c = MFMA(f3h, B2h[g][3], c, 0, 0, 0);
                C[g] = c;
            }
            float h2v[2];
            #pragma unroll
            for (int j = 0; j < 2; ++j) {
                float I = sigf  (C[0][j]);
                float F = sigf  (C[1][j]);
                float G = tanhf_(C[2][j]);
                float O = sigf  (C[3][j]);
                c2[j] = F * c2[j] + I * G;
                h2v[j] = O * tanhf_(c2[j]);
            }
            if (u < H) {
                const unsigned int pk = bf16pk(h2v[0], h2v[1]);
                sA2h[ws][arow][u]     = (unsigned short)pk;
                sA2h[ws][arow + 1][u] = (unsigned short)(pk >> 16);
                sH2f[rs][u][rowA]     = h2v[0];
                sH2f[rs][u][rowA + 1] = h2v[1];
            }
        };

        // ---- pipelined teacher-forced phase ----
        for (int s = 0; s < TIN; ++s) {
            if ((s & 1) == 0) { if (s) l2work(0, 1); }
            else              l2work(1, 0);
            __syncthreads();
        }
        // ---- serial tail ----
        for (int s = TIN; s <= TTOT; ++s) {
            const int rs = s & 1, ws = rs ^ 1;
            l2work(rs, ws);
            __syncthreads();               // B1
            __syncthreads();               // B2
            __syncthreads();               // B3
        }
    } else {
        // ================= AUX WAVES: head + x staging + feedback =================
        auto headw = [&](int slot, int outt) __attribute__((always_inline)) -> float {
            float p = sWlin[kc]      * sH2f[slot][kc][bhead]
                    + sWlin[kc + 32] * sH2f[slot][kc + 32][bhead];
            p += __shfl_xor(p, 1);  p += __shfl_xor(p, 2);  p += __shfl_xor(p, 4);
            p += __shfl_xor(p, 8);  p += __shfl_xor(p, 16);
            float val = p + blin;
            if (kc == 0) sOut[bhead][outt] = val;
            return val;
        };

        // ---- teacher phase: head(s-2) + stage x(s+1) ----
        for (int s = 0; s < TIN; ++s) {
            const int ws = (s & 1) ? 0 : 1;
            if (s >= 2) headw(ws, s - 2);      // sH2f[ws] written last interval
            if ((wv == 8) && (lane < 8) && (s + 1 < TIN)) {
                unsigned short hh; float lo; bf16split(sIn[lane][s + 1], hh, lo);
                sA1h[ws][(lane & 2) ? lane + 6 : lane][51] = hh;
                sXlo[ws][lane] = lo;
            }
            __syncthreads();
        }
        // ---- serial tail: head(s-1) + feedback x(s) ----
        for (int s = TIN; s <= TTOT; ++s) {
            const int rs = s & 1, ws = rs ^ 1;
            __syncthreads();               // B1: h2(s-1) -> sH2f[rs] visible
            {
                float val = headw(rs, s - 1);
                if (kc == 0 && s < TTOT) { // feedback x(s) = out(s-1)
                    unsigned short hh; float lo; bf16split(val, hh, lo);
                    sA1h[rs][(bhead & 2) ? bhead + 6 : bhead][51] = hh;
                    sXlo[rs][bhead] = lo;
                }
                if (s == TIN) headw(ws, s - 2);   // gap: out(TIN-2)
            }
            __syncthreads();               // B2: x(s) visible
            __syncthreads();               // B3
        }
    }

    // ---- write buffered outputs back: 8 rows x 544 f32, float4 coalesced ----
    __syncthreads();
    for (int i = tid; i < BTILE * (TTOT / 4); i += NTHR) {
        const int r = i / (TTOT / 4);
        const int c = i - r * (TTOT / 4);
        *(float4v*)&out[(size_t)(b0 + r) * TTOT + c * 4] =
            *(const float4v*)&sOut[r][c * 4];
    }
}

extern "C" void kernel_launch(void* const* d_in, const int* in_sizes, int n_in,
                              void* d_out, int out_size, void* d_ws, size_t ws_size,
                              hipStream_t stream) {
    const float* input = (const float*)d_in[0];
    const float* W_ih1 = (const float*)d_in[1];
    const float* W_hh1 = (const float*)d_in[2];
    const float* b_ih1 = (const float*)d_in[3];
    const float* b_hh1 = (const float*)d_in[4];
    const float* W_ih2 = (const float*)d_in[5];
    const float* W_hh2 = (const float*)d_in[6];
    const float* b_ih2 = (const float*)d_in[7];
    const float* b_hh2 = (const float*)d_in[8];
    const float* W_lin = (const float*)d_in[9];
    const float* b_lin = (const float*)d_in[10];
    // d_in[11] = future (=32), compiled in.
    float* out = (float*)d_out;

    lstm_seq<<<dim3(256), dim3(NTHR), 0, stream>>>(input, W_ih1, W_hh1, b_ih1, b_hh1,
                                                   W_ih2, W_hh2, b_ih2, b_hh2,
                                                   W_lin, b_lin, out);
}